// Round 1
// 611.617 us; speedup vs baseline: 1.0978x; 1.0978x over previous
//
#include <hip/hip_runtime.h>

// ---------------------------------------------------------------------------
// ShiftedWindowAttention (Swin block, no mask): B=32, H=W=56, C=384, ws=7,
// shift=3, heads=12, hd=32.
//   prep:      weights -> bf16 [n][k]; bias -> C-frag order (+mask);
//              x -> bf16 (XB, aliases AO region)
//   qkv_gemm:  XB @ Wq^T -> Q,K,V bf16 [win][head][49][32], 128x128 tiles,
//              XCD-grouped N-fastest swizzle for A reuse in per-XCD L2
//   attn:      4 waves/block, 1 wave per (win,head); V via LDS; QK^T MFMA ->
//              exp(+bias) -> rowsum -> P via LDS -> PV MFMA -> scatter AO
//   proj_gemm: AO @ Wp^T + proj_b -> out fp32 (same swizzled 128x128 GEMM)
// R3 fix: V LDS staging loop was idx<196, must be idx<392 (49 rows x 8 uint2)
//         -> rows 25..48 of V were uninitialized LDS (NaN source).
// R4 (this round): both GEMMs staged via global_load_lds width=16 (direct
//         HBM->LDS, no VGPR round trip), linear [128][32] LDS tiles.
//         m97/m151 lever: 646->874 TF at this exact tile shape.
// ---------------------------------------------------------------------------

typedef __attribute__((ext_vector_type(8))) short short8;
typedef __attribute__((ext_vector_type(4))) float floatx4;

#define CDIM  384
#define QKVN  1152
#define MROWS 100352      // 32*3136
#define LROW  3136        // 56*56

static constexpr size_t QKV_ELEMS = 38535168ull;   // 2048*12*49*32
static constexpr size_t OFF_Q    = 0;
static constexpr size_t OFF_K    = OFF_Q  + QKV_ELEMS * 2 + 4096;
static constexpr size_t OFF_V    = OFF_K  + QKV_ELEMS * 2 + 4096;
static constexpr size_t OFF_AO   = OFF_V  + QKV_ELEMS * 2 + 4096;  // also XB (x as bf16) before attn runs
static constexpr size_t OFF_WQ   = OFF_AO + (size_t)MROWS * CDIM * 2 + 4096;
static constexpr size_t OFF_WP   = OFF_WQ + (size_t)QKVN * CDIM * 2 + 256;
static constexpr size_t OFF_BIAS = OFF_WP + (size_t)CDIM * CDIM * 2 + 256;

__device__ __forceinline__ unsigned short f2bf(float f) {
  unsigned int u = __float_as_uint(f);
  unsigned int lsb = (u >> 16) & 1u;
  u += 0x7fffu + lsb;
  return (unsigned short)(u >> 16);
}

// direct global -> LDS async copy, 16B per lane. LDS dest must be
// wave-uniform base (+ lane*16 implicit); global src is per-lane.
__device__ __forceinline__ void gl2lds16(const void* g, void* l) {
  __builtin_amdgcn_global_load_lds(
      (const __attribute__((address_space(1))) unsigned int*)g,
      (__attribute__((address_space(3))) unsigned int*)l, 16, 0, 0);
}

// ---------------------------------------------------------------------------
// prep: weight transpose/convert + bias in C-frag order + x -> bf16
// ---------------------------------------------------------------------------
__global__ __launch_bounds__(256) void prep_kernel(
    const float* __restrict__ x, const float* __restrict__ qkv_w,
    const float* __restrict__ proj_w, const float* __restrict__ rbt,
    char* __restrict__ ws) {
  unsigned short* Wq = (unsigned short*)(ws + OFF_WQ);
  unsigned short* Wp = (unsigned short*)(ws + OFF_WP);
  unsigned short* XB = (unsigned short*)(ws + OFF_AO);
  float* biasp = (float*)(ws + OFF_BIAS);
  const int tid = blockIdx.x * blockDim.x + threadIdx.x;
  const int stride = gridDim.x * blockDim.x;
  for (int idx = tid; idx < QKVN * CDIM; idx += stride) {
    int n = idx / CDIM, k = idx - n * CDIM;
    Wq[idx] = f2bf(qkv_w[(size_t)k * QKVN + n]);
  }
  for (int idx = tid; idx < CDIM * CDIM; idx += stride) {
    int n = idx / CDIM, k = idx - n * CDIM;
    Wp[idx] = f2bf(proj_w[(size_t)k * CDIM + n]);
  }
  for (int idx = tid; idx < 12 * 64 * 64; idx += stride) {
    int h = idx / 4096;
    int rem = idx - h * 4096;
    int lane = rem / 64;
    int e = rem - lane * 64;        // (fm*4+fn)*4 + r
    int fm = e >> 4, fn = (e >> 2) & 3, r = e & 3;
    int row = fm * 16 + (lane >> 4) * 4 + r;
    int col = fn * 16 + (lane & 15);
    float v = -1e30f;
    if (row < 49 && col < 49) {
      int i = row / 7, j = row - i * 7;
      int k2 = col / 7, l2 = col - k2 * 7;
      int rpi = (i - k2 + 6) * 13 + (j - l2 + 6);
      v = rbt[rpi * 12 + h];
    }
    biasp[idx] = v;
  }
  // x fp32 -> bf16, 8 elems/iter
  const size_t n8 = (size_t)MROWS * CDIM / 8;   // 4,816,896
  for (size_t idx = tid; idx < n8; idx += stride) {
    const float4* s = (const float4*)(x + idx * 8);
    float4 f0 = s[0], f1 = s[1];
    uint4 o;
    o.x = (unsigned)f2bf(f0.x) | ((unsigned)f2bf(f0.y) << 16);
    o.y = (unsigned)f2bf(f0.z) | ((unsigned)f2bf(f0.w) << 16);
    o.z = (unsigned)f2bf(f1.x) | ((unsigned)f2bf(f1.y) << 16);
    o.w = (unsigned)f2bf(f1.z) | ((unsigned)f2bf(f1.w) << 16);
    ((uint4*)XB)[idx] = o;
  }
}

// ---------------------------------------------------------------------------
// QKV GEMM: 100352x1152 = XB(bf16) @ Wq^T.  BM=128 BN=128 BK=32, 256 thr =
// 4 waves 2x2, per-wave 64x64 = 4x4 frags of 16x16x32 bf16.
// Staging: global_load_lds 16B/lane; wave wv covers rows [wv*32, wv*32+32)
// of both tiles (2 issues of 16 rows each per matrix).
// Linear grid 7056, swizzle: xcd=L%8, slot=L/8, m=(slot/9)*8+xcd, n=slot%9
// -> all 9 N-blocks of an M-row-block on one XCD (A fetched once from HBM).
// Epilogue: +bias, Q*=1/sqrt(32), scatter to [win][head][n][d] bf16.
// ---------------------------------------------------------------------------
__global__ __launch_bounds__(256) void qkv_gemm(
    const float* __restrict__ qkv_b, char* __restrict__ ws) {
  __shared__ unsigned short As[128][32];
  __shared__ unsigned short Bs[128][32];
  const unsigned short* XB = (const unsigned short*)(ws + OFF_AO);
  const unsigned short* Wq = (const unsigned short*)(ws + OFF_WQ);
  unsigned short* Qb = (unsigned short*)(ws + OFF_Q);
  unsigned short* Kb = (unsigned short*)(ws + OFF_K);
  unsigned short* Vb = (unsigned short*)(ws + OFF_V);
  const int L = blockIdx.x;
  const int xcd = L & 7, slot = L >> 3;
  const int g9 = slot / 9;
  const int m0 = (g9 * 8 + xcd) * 128;
  const int n0 = (slot - g9 * 9) * 128;
  const int t = threadIdx.x;
  const int lane = t & 63, li = lane & 15, qd = lane >> 4;
  const int wv = t >> 6, wm = wv >> 1, wn = wv & 1;
  // staging coords: lane -> (row within 16-row chunk, 16B chunk in row)
  const int ld_r = lane >> 2;          // 0..15
  const int ld_c = (lane & 3) * 8;     // shorts
  const unsigned short* agp = XB + (size_t)(m0 + wv * 32 + ld_r) * CDIM + ld_c;
  const unsigned short* bgp = Wq + (size_t)(n0 + wv * 32 + ld_r) * CDIM + ld_c;
  floatx4 acc[4][4] = {};
  for (int k0 = 0; k0 < CDIM; k0 += 32) {
    gl2lds16(agp + k0,             &As[wv * 32][0]);
    gl2lds16(agp + k0 + 16 * CDIM, &As[wv * 32 + 16][0]);
    gl2lds16(bgp + k0,             &Bs[wv * 32][0]);
    gl2lds16(bgp + k0 + 16 * CDIM, &Bs[wv * 32 + 16][0]);
    __syncthreads();
    short8 a[4], b[4];
#pragma unroll
    for (int f = 0; f < 4; f++)
      a[f] = *(const short8*)&As[wm * 64 + f * 16 + li][qd * 8];
#pragma unroll
    for (int f = 0; f < 4; f++)
      b[f] = *(const short8*)&Bs[wn * 64 + f * 16 + li][qd * 8];
#pragma unroll
    for (int i = 0; i < 4; i++)
#pragma unroll
      for (int j = 0; j < 4; j++)
        acc[i][j] = __builtin_amdgcn_mfma_f32_16x16x32_bf16(a[i], b[j], acc[i][j], 0, 0, 0);
    __syncthreads();
  }
  // epilogue: each 128-wide N-tile lies entirely in one of Q/K/V (384 = 3*128)
  const int which = n0 / CDIM;
  unsigned short* dst = which == 0 ? Qb : (which == 1 ? Kb : Vb);
  const float mul = (which == 0) ? 0.17677669529663689f : 1.0f;
#pragma unroll
  for (int i = 0; i < 4; i++) {
    int winr[4], nidxr[4];
#pragma unroll
    for (int r = 0; r < 4; r++) {
      int m = m0 + wm * 64 + i * 16 + qd * 4 + r;
      int b_ = m / LROW, l = m - b_ * LROW;
      int y = l / 56, xx = l - y * 56;
      int yr = y + 53; if (yr >= 56) yr -= 56;   // roll -3
      int xr = xx + 53; if (xr >= 56) xr -= 56;
      winr[r] = b_ * 64 + (yr / 7) * 8 + (xr / 7);
      nidxr[r] = (yr % 7) * 7 + (xr % 7);
    }
#pragma unroll
    for (int j = 0; j < 4; j++) {
      int c = n0 + wn * 64 + j * 16 + li;
      int cc = c - which * CDIM;
      int head = cc >> 5, d = cc & 31;
      float bval = qkv_b[c];
#pragma unroll
      for (int r = 0; r < 4; r++) {
        size_t off = ((size_t)(winr[r] * 12 + head) * 49 + nidxr[r]) * 32 + d;
        dst[off] = f2bf((acc[i][j][r] + bval) * mul);
      }
    }
  }
}

// ---------------------------------------------------------------------------
// Attention: 256 thr = 4 waves, wave wv handles head blockIdx.y*4+wv of
// window blockIdx.x.  Per-wave LDS region SMEM[wv]: first holds V (stride-34
// layout, rows 49..63 zeroed), V frags -> regs, then overwritten by P
// (stride-72).  No __syncthreads (no cross-wave sharing).
// ---------------------------------------------------------------------------
__global__ __launch_bounds__(256) void attn_kernel(char* __restrict__ ws) {
  __shared__ unsigned short SMEM[4][64 * 72];
  const int win = blockIdx.x;
  const int t = threadIdx.x, wv = t >> 6, lane = t & 63;
  const int h = blockIdx.y * 4 + wv;
  const int li = lane & 15, qd = lane >> 4;
  unsigned short* Sm = &SMEM[wv][0];
  const size_t whoff = (size_t)(win * 12 + h) * 49 * 32;
  const unsigned short* Qb = (const unsigned short*)(ws + OFF_Q) + whoff;
  const unsigned short* Kb = (const unsigned short*)(ws + OFF_K) + whoff;
  const unsigned short* Vb = (const unsigned short*)(ws + OFF_V) + whoff;
  const float* biasp = (const float*)(ws + OFF_BIAS) + ((size_t)h * 64 + lane) * 64;

  // stage V: 49 rows x 32 cols bf16 = 392 uint2, LDS stride 34
  {
    const uint2* vsrc = (const uint2*)Vb;
    for (int idx = lane; idx < 392; idx += 64) {
      uint2 d = vsrc[idx];
      unsigned short* p = Sm + (idx >> 3) * 34 + (idx & 7) * 4;
      *(unsigned int*)p = d.x;
      *(unsigned int*)(p + 2) = d.y;
    }
    for (int idx = lane; idx < 120; idx += 64) {   // zero pad rows 49..63
      unsigned short* p = Sm + (49 + (idx >> 3)) * 34 + (idx & 7) * 4;
      *(unsigned int*)p = 0;
      *(unsigned int*)(p + 2) = 0;
    }
  }

  short8 qa[4], kb4[4];
#pragma unroll
  for (int f = 0; f < 4; f++) {
    qa[f] = *(const short8*)(Qb + (f * 16 + li) * 32 + qd * 8);
    kb4[f] = *(const short8*)(Kb + (f * 16 + li) * 32 + qd * 8);
  }
  floatx4 s[4][4] = {};
#pragma unroll
  for (int i = 0; i < 4; i++)
#pragma unroll
    for (int j = 0; j < 4; j++)
      s[i][j] = __builtin_amdgcn_mfma_f32_16x16x32_bf16(qa[i], kb4[j], s[i][j], 0, 0, 0);

  // V B-frags from LDS (before P overwrites the region)
  short8 vb[2][2];
#pragma unroll
  for (int ss = 0; ss < 2; ss++)
#pragma unroll
    for (int nf = 0; nf < 2; nf++) {
      short8 tmp;
#pragma unroll
      for (int j = 0; j < 8; j++)
        tmp[j] = (short)Sm[(ss * 32 + qd * 8 + j) * 34 + nf * 16 + li];
      vb[ss][nf] = tmp;
    }

  float rsum[4][4];
#pragma unroll
  for (int fm = 0; fm < 4; fm++) {
#pragma unroll
    for (int fn = 0; fn < 4; fn++) {
      floatx4 bv = *(const floatx4*)(biasp + (fm * 4 + fn) * 4);
#pragma unroll
      for (int r = 0; r < 4; r++)
        s[fm][fn][r] = __expf(s[fm][fn][r] + bv[r]);
    }
#pragma unroll
    for (int r = 0; r < 4; r++) {
      float v = s[fm][0][r] + s[fm][1][r] + s[fm][2][r] + s[fm][3][r];
      v += __shfl_xor(v, 1);
      v += __shfl_xor(v, 2);
      v += __shfl_xor(v, 4);
      v += __shfl_xor(v, 8);
      rsum[fm][r] = v;
    }
#pragma unroll
    for (int fn = 0; fn < 4; fn++)
#pragma unroll
      for (int r = 0; r < 4; r++)
        Sm[(fm * 16 + qd * 4 + r) * 72 + fn * 16 + li] = f2bf(s[fm][fn][r]);
  }

  floatx4 o[4][2] = {};
#pragma unroll
  for (int fm = 0; fm < 4; fm++)
#pragma unroll
    for (int ss = 0; ss < 2; ss++) {
      short8 pa = *(const short8*)&Sm[(fm * 16 + li) * 72 + ss * 32 + qd * 8];
#pragma unroll
      for (int nf = 0; nf < 2; nf++)
        o[fm][nf] = __builtin_amdgcn_mfma_f32_16x16x32_bf16(pa, vb[ss][nf], o[fm][nf], 0, 0, 0);
    }

  unsigned short* AO = (unsigned short*)(ws + OFF_AO);
  const int b_ = win >> 6, wrem = win & 63, wy = wrem >> 3, wx = wrem & 7;
#pragma unroll
  for (int fm = 0; fm < 4; fm++)
#pragma unroll
    for (int r = 0; r < 4; r++) {
      int n = fm * 16 + qd * 4 + r;
      if (n >= 49) continue;
      float inv = 1.0f / rsum[fm][r];
      int i_ = n / 7, j_ = n - i_ * 7;
      int y = wy * 7 + i_ + 3;  if (y >= 56) y -= 56;   // un-roll +3
      int xx = wx * 7 + j_ + 3; if (xx >= 56) xx -= 56;
      size_t base = ((size_t)b_ * LROW + y * 56 + xx) * CDIM + h * 32;
#pragma unroll
      for (int nf = 0; nf < 2; nf++)
        AO[base + nf * 16 + li] = f2bf(o[fm][nf][r] * inv);
    }
}

// ---------------------------------------------------------------------------
// Proj GEMM: out(100352x384 fp32) = AO(bf16) @ Wp^T + proj_b.  Same swizzled
// 128x128 structure with global_load_lds staging; grid 2352: m=(slot/3)*8+xcd,
// n=slot%3.
// ---------------------------------------------------------------------------
__global__ __launch_bounds__(256) void proj_gemm(
    const float* __restrict__ proj_b, char* __restrict__ ws,
    float* __restrict__ out) {
  __shared__ unsigned short As[128][32];
  __shared__ unsigned short Bs[128][32];
  const unsigned short* AO = (const unsigned short*)(ws + OFF_AO);
  const unsigned short* Wp = (const unsigned short*)(ws + OFF_WP);
  const int L = blockIdx.x;
  const int xcd = L & 7, slot = L >> 3;
  const int g3 = slot / 3;
  const int m0 = (g3 * 8 + xcd) * 128;
  const int n0 = (slot - g3 * 3) * 128;
  const int t = threadIdx.x;
  const int lane = t & 63, li = lane & 15, qd = lane >> 4;
  const int wv = t >> 6, wm = wv >> 1, wn = wv & 1;
  const int ld_r = lane >> 2;
  const int ld_c = (lane & 3) * 8;
  const unsigned short* agp = AO + (size_t)(m0 + wv * 32 + ld_r) * CDIM + ld_c;
  const unsigned short* bgp = Wp + (size_t)(n0 + wv * 32 + ld_r) * CDIM + ld_c;
  floatx4 acc[4][4] = {};
  for (int k0 = 0; k0 < CDIM; k0 += 32) {
    gl2lds16(agp + k0,             &As[wv * 32][0]);
    gl2lds16(agp + k0 + 16 * CDIM, &As[wv * 32 + 16][0]);
    gl2lds16(bgp + k0,             &Bs[wv * 32][0]);
    gl2lds16(bgp + k0 + 16 * CDIM, &Bs[wv * 32 + 16][0]);
    __syncthreads();
    short8 a[4], b[4];
#pragma unroll
    for (int f = 0; f < 4; f++)
      a[f] = *(const short8*)&As[wm * 64 + f * 16 + li][qd * 8];
#pragma unroll
    for (int f = 0; f < 4; f++)
      b[f] = *(const short8*)&Bs[wn * 64 + f * 16 + li][qd * 8];
#pragma unroll
    for (int i = 0; i < 4; i++)
#pragma unroll
      for (int j = 0; j < 4; j++)
        acc[i][j] = __builtin_amdgcn_mfma_f32_16x16x32_bf16(a[i], b[j], acc[i][j], 0, 0, 0);
    __syncthreads();
  }
#pragma unroll
  for (int i = 0; i < 4; i++)
#pragma unroll
    for (int j = 0; j < 4; j++) {
      int c = n0 + wn * 64 + j * 16 + li;
      float bv = proj_b[c];
#pragma unroll
      for (int r = 0; r < 4; r++) {
        int m = m0 + wm * 64 + i * 16 + qd * 4 + r;
        out[(size_t)m * CDIM + c] = acc[i][j][r] + bv;
      }
    }
}

extern "C" void kernel_launch(void* const* d_in, const int* in_sizes, int n_in,
                              void* d_out, int out_size, void* d_ws, size_t ws_size,
                              hipStream_t stream) {
  const float* x      = (const float*)d_in[0];
  const float* qkv_w  = (const float*)d_in[1];
  const float* qkv_b  = (const float*)d_in[2];
  const float* proj_w = (const float*)d_in[3];
  const float* proj_b = (const float*)d_in[4];
  const float* rbt    = (const float*)d_in[5];
  char* ws = (char*)d_ws;
  float* out = (float*)d_out;

  prep_kernel<<<2048, 256, 0, stream>>>(x, qkv_w, proj_w, rbt, ws);
  qkv_gemm<<<7056, 256, 0, stream>>>(qkv_b, ws);
  attn_kernel<<<dim3(2048, 3), 256, 0, stream>>>(ws);
  proj_gemm<<<2352, 256, 0, stream>>>(proj_b, ws, out);
}